// Round 2
// baseline (465.438 us; speedup 1.0000x reference)
//
#include <hip/hip_runtime.h>
#include <math.h>

#define Bsz   256
#define Nn    2048
#define Md    64
#define CSd   512
#define INPd  256
#define OUTd  256
#define KTOT  832      // INP + M + CS
#define PSTRIDE 272    // per-batch param block (floats)

__device__ __forceinline__ float sigmoidf_(float x){ return 1.f/(1.f+expf(-x)); }
__device__ __forceinline__ float softplusf_(float x){ return fmaxf(x,0.f) + log1pf(expf(-fabsf(x))); }

// ---------------- Kernel 1: gates = [x,prev_read,h] @ [W_ih|W_hh]^T + b_ih + b_hh
__global__ __launch_bounds__(256) void k_gates(
    const float* __restrict__ x, const float* __restrict__ prev_read, const float* __restrict__ h,
    const float* __restrict__ W_ih, const float* __restrict__ W_hh,
    const float* __restrict__ b_ih, const float* __restrict__ b_hh,
    float* __restrict__ gates)
{
  __shared__ float As[64][17];
  __shared__ float Bs[64][17];
  const int tid = threadIdx.x;
  const int tx = tid & 15, ty = tid >> 4;
  const int row0 = blockIdx.y * 64;   // batch rows
  const int col0 = blockIdx.x * 64;   // gate units
  float acc[4][4] = {};
  const int f = tid * 4;
  const int m = f >> 4, kk0 = f & 15;
  for (int k0 = 0; k0 < KTOT; k0 += 16) {
    // A tile: 64 rows x 16 k
    {
      int b = row0 + m;
      #pragma unroll
      for (int i = 0; i < 4; ++i) {
        int k = k0 + kk0 + i;
        float v;
        if (k < INPd)            v = x[b*INPd + k];
        else if (k < INPd+Md)    v = prev_read[b*Md + (k-INPd)];
        else                     v = h[b*CSd + (k-INPd-Md)];
        As[m][kk0+i] = v;
      }
      int j = col0 + m;
      #pragma unroll
      for (int i = 0; i < 4; ++i) {
        int k = k0 + kk0 + i;
        float v = (k < INPd+Md) ? W_ih[j*(INPd+Md) + k] : W_hh[j*CSd + (k-INPd-Md)];
        Bs[m][kk0+i] = v;
      }
    }
    __syncthreads();
    #pragma unroll
    for (int kk = 0; kk < 16; ++kk) {
      float a[4], bb[4];
      #pragma unroll
      for (int i=0;i<4;++i) a[i]  = As[ty*4+i][kk];
      #pragma unroll
      for (int j=0;j<4;++j) bb[j] = Bs[tx*4+j][kk];
      #pragma unroll
      for (int i=0;i<4;++i)
        #pragma unroll
        for (int j=0;j<4;++j)
          acc[i][j] += a[i]*bb[j];
    }
    __syncthreads();
  }
  #pragma unroll
  for (int i=0;i<4;++i){
    int b = row0 + ty*4 + i;
    #pragma unroll
    for (int j=0;j<4;++j){
      int col = col0 + tx*4 + j;
      gates[b*2048 + col] = acc[i][j] + b_ih[col] + b_hh[col];
    }
  }
}

// ---------------- Kernel 2: LSTM elementwise
__global__ __launch_bounds__(256) void k_lstm(const float* __restrict__ gates,
    const float* __restrict__ c, float* __restrict__ h_new, float* __restrict__ c_new)
{
  int idx = blockIdx.x*256 + threadIdx.x;  // B*CS = 131072
  int b = idx >> 9, j = idx & 511;
  const float* g = gates + b*2048;
  float ig = sigmoidf_(g[j]);
  float fg = sigmoidf_(g[512+j]);
  float gg = tanhf(g[1024+j]);
  float og = sigmoidf_(g[1536+j]);
  float cn = fg * c[idx] + ig * gg;
  c_new[idx] = cn;
  h_new[idx] = og * tanhf(cn);
}

// ---------------- Kernel 3: head projections + addressing params
__global__ __launch_bounds__(256) void k_heads(
    const float* __restrict__ h_new,
    const float* __restrict__ W_r, const float* __restrict__ b_r,
    const float* __restrict__ W_w, const float* __restrict__ b_w,
    float* __restrict__ params)
{
  __shared__ float hs[CSd];
  __shared__ float ob[268];   // [0,70)=read_out, [70,268)=write_out
  int b = blockIdx.x, t = threadIdx.x;
  hs[t]       = h_new[b*CSd + t];
  hs[t + 256] = h_new[b*CSd + t + 256];
  __syncthreads();
  // 268 rows with 256 threads: strided loop (fixes ob[256..267] never written)
  for (int r = t; r < 268; r += 256) {
    const float* wrow; float bias;
    if (r < 70) { wrow = W_r + r*CSd;      bias = b_r[r]; }
    else        { wrow = W_w + (r-70)*CSd; bias = b_w[r-70]; }
    float s = bias;
    #pragma unroll 8
    for (int k=0;k<CSd;++k) s += wrow[k]*hs[k];
    ob[r] = s;
  }
  __syncthreads();
  float* P = params + b*PSTRIDE;
  if (t < 64)       P[t] = ob[t];                           // k_r
  else if (t < 128) P[t] = ob[70 + (t-64)];                 // k_w
  else if (t < 192) P[t] = sigmoidf_(ob[140 + (t-128)]);    // erase
  else              P[t] = ob[204 + (t-192)];               // add
  if (t == 0) {
    float* S = P + 256;
    float nk = 0.f;
    for (int i=0;i<64;++i){ float v=ob[i]; nk += v*v; }
    S[6] = 1.f/(sqrtf(nk)+1e-8f);
    nk = 0.f;
    for (int i=0;i<64;++i){ float v=ob[70+i]; nk += v*v; }
    S[13] = 1.f/(sqrtf(nk)+1e-8f);
    // read head scalars
    S[0] = softplusf_(ob[64]);
    S[1] = sigmoidf_(ob[65]);
    {
      float m3 = fmaxf(ob[66], fmaxf(ob[67], ob[68]));
      float e0=expf(ob[66]-m3), e1=expf(ob[67]-m3), e2=expf(ob[68]-m3);
      float es = e0+e1+e2;
      S[2]=e0/es; S[3]=e1/es; S[4]=e2/es;
    }
    S[5] = 1.f + softplusf_(ob[69]);
    // write head scalars
    S[7] = softplusf_(ob[134]);
    S[8] = sigmoidf_(ob[135]);
    {
      float m3 = fmaxf(ob[136], fmaxf(ob[137], ob[138]));
      float e0=expf(ob[136]-m3), e1=expf(ob[137]-m3), e2=expf(ob[138]-m3);
      float es = e0+e1+e2;
      S[9]=e0/es; S[10]=e1/es; S[11]=e2/es;
    }
    S[12] = 1.f + softplusf_(ob[139]);
  }
}

// ---------------- Kernel 4: pass A over memory — beta*cosine-sim for both heads
__global__ __launch_bounds__(256) void k_sim(
    const float* __restrict__ mem, const float* __restrict__ params,
    float* __restrict__ a_r, float* __restrict__ a_w)
{
  int b = blockIdx.y;
  int n = blockIdx.x*16 + (threadIdx.x >> 4);
  int chunk = threadIdx.x & 15;
  float4 v = ((const float4*)mem)[(b*Nn + n)*16 + chunk];
  const float* P = params + b*PSTRIDE;
  float4 kr = ((const float4*)P)[chunk];
  float4 kw = ((const float4*)(P+64))[chunk];
  float ss = v.x*v.x + v.y*v.y + v.z*v.z + v.w*v.w;
  float pr = v.x*kr.x + v.y*kr.y + v.z*kr.z + v.w*kr.w;
  float pw = v.x*kw.x + v.y*kw.y + v.z*kw.z + v.w*kw.w;
  #pragma unroll
  for (int off=8; off; off>>=1) {
    ss += __shfl_xor(ss, off);
    pr += __shfl_xor(pr, off);
    pw += __shfl_xor(pw, off);
  }
  if (chunk == 0) {
    float inv_nm = 1.f/(sqrtf(ss)+1e-8f);
    const float* S = P + 256;
    a_r[b*Nn+n] = S[0] * pr * S[6]  * inv_nm;
    a_w[b*Nn+n] = S[7] * pw * S[13] * inv_nm;
  }
}

// ---------------- Kernel 5: softmax -> interpolate -> shift -> sharpen -> normalize
__device__ __forceinline__ float block_reduce512(float val, float* red, int t, bool ismax){
  #pragma unroll
  for (int off=32; off; off>>=1)
    val = ismax ? fmaxf(val, __shfl_xor(val,off)) : val + __shfl_xor(val,off);
  __syncthreads();
  if ((t&63)==0) red[t>>6] = val;
  __syncthreads();
  float r = red[0];
  if (ismax) { for (int i=1;i<8;++i) r = fmaxf(r, red[i]); }
  else       { for (int i=1;i<8;++i) r += red[i]; }
  return r;
}

__global__ __launch_bounds__(512) void k_weights(
    const float* __restrict__ a_r, const float* __restrict__ a_w,
    const float* __restrict__ read_w, const float* __restrict__ write_w,
    const float* __restrict__ params,
    float* __restrict__ w_read, float* __restrict__ w_write)
{
  __shared__ float wg[Nn];
  __shared__ float red[8];
  int b = blockIdx.x;
  int which = blockIdx.y;
  const float* a    = which ? a_w     : a_r;
  const float* prev = which ? write_w : read_w;
  float* outw       = which ? w_write : w_read;
  const float* S = params + b*PSTRIDE + 256 + (which ? 7 : 0);
  float g = S[1], s0 = S[2], s1 = S[3], s2 = S[4], gamma = S[5];
  int t = threadIdx.x;
  float v[4];
  #pragma unroll
  for (int i=0;i<4;++i) v[i] = a[b*Nn + t*4+i];
  float lmax = fmaxf(fmaxf(v[0],v[1]), fmaxf(v[2],v[3]));
  float mx = block_reduce512(lmax, red, t, true);
  float e[4]; float ps = 0.f;
  #pragma unroll
  for (int i=0;i<4;++i){ e[i] = expf(v[i]-mx); ps += e[i]; }
  float denom = block_reduce512(ps, red, t, false);
  float inv = 1.f/denom;
  #pragma unroll
  for (int i=0;i<4;++i){
    float wc = e[i]*inv;
    wg[t*4+i] = g*wc + (1.f-g)*prev[b*Nn + t*4+i];
  }
  __syncthreads();
  float wp[4]; float psum = 0.f;
  #pragma unroll
  for (int i=0;i<4;++i){
    int n = t*4+i;
    float wsv = s0*wg[(n+Nn-1)&(Nn-1)] + s1*wg[n] + s2*wg[(n+1)&(Nn-1)];
    wp[i] = powf(wsv, gamma);
    psum += wp[i];
  }
  float tot = block_reduce512(psum, red, t, false);
  float invt = 1.f/(tot + 1e-8f);
  #pragma unroll
  for (int i=0;i<4;++i) outw[b*Nn + t*4+i] = wp[i]*invt;
}

// ---------------- Kernel 6: pass B — memory_new + read_vec accumulation
__global__ __launch_bounds__(256) void k_memupd(
    const float* __restrict__ mem, const float* __restrict__ params,
    const float* __restrict__ w_read, const float* __restrict__ w_write,
    float* __restrict__ mem_new, float* __restrict__ read_vec)
{
  __shared__ __align__(16) float er[64];
  __shared__ __align__(16) float ad[64];
  __shared__ float4 part[64];
  int b = blockIdx.y;
  int n0 = blockIdx.x * 64;
  int t = threadIdx.x;
  const float* P = params + b*PSTRIDE;
  if (t < 64)       er[t]    = P[128+t];
  else if (t < 128) ad[t-64] = P[192+(t-64)];
  __syncthreads();
  int chunk = t & 15;
  int rr = t >> 4;
  float4 e4 = ((const float4*)er)[chunk];
  float4 a4 = ((const float4*)ad)[chunk];
  float4 acc = {0.f,0.f,0.f,0.f};
  #pragma unroll
  for (int p = 0; p < 4; ++p) {
    int n = n0 + p*16 + rr;
    float4 v = ((const float4*)mem)[(b*Nn+n)*16 + chunk];
    float ww = w_write[b*Nn+n];
    float wr = w_read[b*Nn+n];
    float4 o;
    o.x = v.x*(1.f-ww*e4.x) + ww*a4.x;
    o.y = v.y*(1.f-ww*e4.y) + ww*a4.y;
    o.z = v.z*(1.f-ww*e4.z) + ww*a4.z;
    o.w = v.w*(1.f-ww*e4.w) + ww*a4.w;
    ((float4*)mem_new)[(b*Nn+n)*16 + chunk] = o;
    acc.x += wr*v.x; acc.y += wr*v.y; acc.z += wr*v.z; acc.w += wr*v.w;
  }
  #pragma unroll
  for (int off = 16; off <= 32; off <<= 1) {
    acc.x += __shfl_xor(acc.x, off);
    acc.y += __shfl_xor(acc.y, off);
    acc.z += __shfl_xor(acc.z, off);
    acc.w += __shfl_xor(acc.w, off);
  }
  int wave = t >> 6;
  int lane = t & 63;
  if (lane < 16) part[wave*16 + chunk] = acc;
  __syncthreads();
  if (t < 16) {
    float4 s = part[t];
    for (int w=1; w<4; ++w){ float4 q = part[w*16+t]; s.x+=q.x; s.y+=q.y; s.z+=q.z; s.w+=q.w; }
    atomicAdd(&read_vec[b*64 + t*4+0], s.x);
    atomicAdd(&read_vec[b*64 + t*4+1], s.y);
    atomicAdd(&read_vec[b*64 + t*4+2], s.z);
    atomicAdd(&read_vec[b*64 + t*4+3], s.w);
  }
}

// ---------------- Kernel 7: out = [h_new, read_vec] @ W_o^T + b_o
__global__ __launch_bounds__(256) void k_out(
    const float* __restrict__ h_new, const float* __restrict__ read_vec,
    const float* __restrict__ W_o, const float* __restrict__ b_o,
    float* __restrict__ out)
{
  __shared__ float vbuf[576];
  int b = blockIdx.x, t = threadIdx.x;
  vbuf[t]     = h_new[b*CSd + t];
  vbuf[t+256] = h_new[b*CSd + t + 256];
  if (t < 64) vbuf[512+t] = read_vec[b*64 + t];
  __syncthreads();
  float s = b_o[t];
  const float* w = W_o + t*576;
  #pragma unroll 8
  for (int k=0;k<576;++k) s += w[k]*vbuf[k];
  out[b*OUTd + t] = s;
}

extern "C" void kernel_launch(void* const* d_in, const int* in_sizes, int n_in,
                              void* d_out, int out_size, void* d_ws, size_t ws_size,
                              hipStream_t stream)
{
  const float* x         = (const float*)d_in[0];
  const float* memory    = (const float*)d_in[1];
  const float* h         = (const float*)d_in[2];
  const float* c         = (const float*)d_in[3];
  const float* read_w    = (const float*)d_in[4];
  const float* write_w   = (const float*)d_in[5];
  const float* prev_read = (const float*)d_in[6];
  const float* W_ih      = (const float*)d_in[7];
  const float* W_hh      = (const float*)d_in[8];
  const float* b_ih      = (const float*)d_in[9];
  const float* b_hh      = (const float*)d_in[10];
  const float* W_r       = (const float*)d_in[11];
  const float* b_r       = (const float*)d_in[12];
  const float* W_w       = (const float*)d_in[13];
  const float* b_w       = (const float*)d_in[14];
  const float* W_o       = (const float*)d_in[15];
  const float* b_o       = (const float*)d_in[16];

  float* out      = (float*)d_out;
  float* mem_new  = out + 256*256;
  float* h_new    = mem_new + (size_t)256*2048*64;
  float* c_new    = h_new + 256*512;
  float* w_read   = c_new + 256*512;
  float* w_write  = w_read + 256*2048;
  float* read_vec = w_write + 256*2048;

  float* ws     = (float*)d_ws;
  float* gates  = ws;                       // 256*2048
  float* params = gates + 256*2048;         // 256*PSTRIDE
  float* a_r    = params + 256*PSTRIDE;     // 256*2048
  float* a_w    = a_r + 256*2048;           // 256*2048

  k_gates  <<<dim3(32,4),   256, 0, stream>>>(x, prev_read, h, W_ih, W_hh, b_ih, b_hh, gates);
  k_lstm   <<<512,          256, 0, stream>>>(gates, c, h_new, c_new);
  k_heads  <<<256,          256, 0, stream>>>(h_new, W_r, b_r, W_w, b_w, params);
  k_sim    <<<dim3(128,256),256, 0, stream>>>(memory, params, a_r, a_w);
  k_weights<<<dim3(256,2),  512, 0, stream>>>(a_r, a_w, read_w, write_w, params, w_read, w_write);
  hipMemsetAsync(read_vec, 0, 256*64*sizeof(float), stream);
  k_memupd <<<dim3(32,256), 256, 0, stream>>>(memory, params, w_read, w_write, mem_new, read_vec);
  k_out    <<<256,          256, 0, stream>>>(h_new, read_vec, W_o, b_o, out);
}

// Round 3
// 375.985 us; speedup vs baseline: 1.2379x; 1.2379x over previous
//
#include <hip/hip_runtime.h>
#include <math.h>

#define Bsz   256
#define Nn    2048
#define Md    64
#define CSd   512
#define INPd  256
#define OUTd  256
#define KTOT  832      // INP + M + CS
#define PSTRIDE 272    // per-batch param block (floats)
#define GSZ   524288   // 256*2048 gates elements (one split partial)

__device__ __forceinline__ float sigmoidf_(float x){ return 1.f/(1.f+expf(-x)); }
__device__ __forceinline__ float softplusf_(float x){ return fmaxf(x,0.f) + log1pf(expf(-fabsf(x))); }

// ---------------- Kernel 1: gates partials, split-K GEMM
// [256 x 832] @ [832 x 2048]^T, tiles 32x64, Ksplit=4 (208 each), grid (32,8,4)
__global__ __launch_bounds__(256) void k_gates(
    const float* __restrict__ x, const float* __restrict__ prev_read, const float* __restrict__ h,
    const float* __restrict__ W_ih, const float* __restrict__ W_hh,
    float* __restrict__ partials)
{
  __shared__ __align__(16) float As[16][34];   // [k][row], stride 136B (8B-mult)
  __shared__ __align__(16) float Bs[16][68];   // [k][col], stride 272B (16B-mult)
  const int t = threadIdx.x;
  const int col0 = blockIdx.x * 64;
  const int row0 = blockIdx.y * 32;
  const int z    = blockIdx.z;          // K split
  const int tx = t & 15;                // 16 col-groups * 4
  const int ty = t >> 4;                // 16 row-groups * 2
  // loader coords
  const int arow = t >> 3;              // 0..31
  const int ak   = (t & 7) * 2;         // 0..14
  const int bcol = t >> 2;              // 0..63
  const int bk   = (t & 3) * 4;         // 0,4,8,12
  const int grow = row0 + arow;
  const int j    = col0 + bcol;

  float acc[2][4] = {};
  for (int kc = 0; kc < 13; ++kc) {
    const int kbase = z * 208 + kc * 16;
    // stage A (32 rows x 16 k)
    #pragma unroll
    for (int i = 0; i < 2; ++i) {
      int k = kbase + ak + i;
      float v;
      if (k < INPd)            v = x[grow*INPd + k];
      else if (k < INPd+Md)    v = prev_read[grow*Md + (k-INPd)];
      else                     v = h[grow*CSd + (k-INPd-Md)];
      As[ak+i][arow] = v;
    }
    // stage B (64 cols x 16 k), float4 along k
    {
      int k = kbase + bk;
      float4 wv;
      if (k < INPd+Md) wv = *(const float4*)&W_ih[j*(INPd+Md) + k];
      else             wv = *(const float4*)&W_hh[j*CSd + (k-INPd-Md)];
      Bs[bk+0][bcol] = wv.x; Bs[bk+1][bcol] = wv.y;
      Bs[bk+2][bcol] = wv.z; Bs[bk+3][bcol] = wv.w;
    }
    __syncthreads();
    #pragma unroll
    for (int kk = 0; kk < 16; ++kk) {
      float2 av = *(const float2*)&As[kk][ty*2];
      float4 bv = *(const float4*)&Bs[kk][tx*4];
      acc[0][0] += av.x*bv.x; acc[0][1] += av.x*bv.y;
      acc[0][2] += av.x*bv.z; acc[0][3] += av.x*bv.w;
      acc[1][0] += av.y*bv.x; acc[1][1] += av.y*bv.y;
      acc[1][2] += av.y*bv.z; acc[1][3] += av.y*bv.w;
    }
    __syncthreads();
  }
  float* part = partials + (size_t)z * GSZ;
  #pragma unroll
  for (int i = 0; i < 2; ++i) {
    float4 v = {acc[i][0], acc[i][1], acc[i][2], acc[i][3]};
    *(float4*)&part[(row0 + ty*2 + i)*2048 + col0 + tx*4] = v;
  }
}

// ---------------- Kernel 2: LSTM elementwise (sums 4 split partials + biases)
__global__ __launch_bounds__(256) void k_lstm(const float* __restrict__ partials,
    const float* __restrict__ c, const float* __restrict__ b_ih, const float* __restrict__ b_hh,
    float* __restrict__ h_new, float* __restrict__ c_new)
{
  int idx = blockIdx.x*256 + threadIdx.x;  // B*CS = 131072
  int b = idx >> 9, jj = idx & 511;
  float g[4];
  #pragma unroll
  for (int q = 0; q < 4; ++q) {
    int col = q*512 + jj;
    float s = b_ih[col] + b_hh[col];
    #pragma unroll
    for (int sp = 0; sp < 4; ++sp) s += partials[(size_t)sp*GSZ + b*2048 + col];
    g[q] = s;
  }
  float ig = sigmoidf_(g[0]);
  float fg = sigmoidf_(g[1]);
  float gg = tanhf(g[2]);
  float og = sigmoidf_(g[3]);
  float cn = fg * c[idx] + ig * gg;
  c_new[idx] = cn;
  h_new[idx] = og * tanhf(cn);
}

// ---------------- Kernel 3: head projections + addressing params (coalesced)
__global__ __launch_bounds__(512) void k_heads(
    const float* __restrict__ h_new,
    const float* __restrict__ W_r, const float* __restrict__ b_r,
    const float* __restrict__ W_w, const float* __restrict__ b_w,
    float* __restrict__ params)
{
  __shared__ float hs[CSd];
  __shared__ float ob[268];   // [0,70)=read_out, [70,268)=write_out
  int b = blockIdx.x, t = threadIdx.x;
  hs[t] = h_new[b*CSd + t];
  __syncthreads();
  int wave = t >> 6, lane = t & 63;
  for (int r = wave; r < 268; r += 8) {
    const float* wrow; float bias;
    if (r < 70) { wrow = W_r + r*CSd;      bias = b_r[r]; }
    else        { wrow = W_w + (r-70)*CSd; bias = b_w[r-70]; }
    float s = 0.f;
    #pragma unroll
    for (int i = 0; i < 8; ++i) s += wrow[i*64 + lane] * hs[i*64 + lane];
    #pragma unroll
    for (int off = 32; off; off >>= 1) s += __shfl_xor(s, off);
    if (lane == 0) ob[r] = s + bias;
  }
  __syncthreads();
  float* P = params + b*PSTRIDE;
  if (t < 256) {
    if (t < 64)       P[t] = ob[t];                           // k_r
    else if (t < 128) P[t] = ob[70 + (t-64)];                 // k_w
    else if (t < 192) P[t] = sigmoidf_(ob[140 + (t-128)]);    // erase
    else              P[t] = ob[204 + (t-192)];               // add
  }
  float* S = P + 256;
  if (wave == 0) {           // ||k_r||
    float v = ob[lane]; float sq = v*v;
    #pragma unroll
    for (int off = 32; off; off >>= 1) sq += __shfl_xor(sq, off);
    if (lane == 0) S[6] = 1.f/(sqrtf(sq)+1e-8f);
  } else if (wave == 1) {    // ||k_w||
    float v = ob[70 + lane]; float sq = v*v;
    #pragma unroll
    for (int off = 32; off; off >>= 1) sq += __shfl_xor(sq, off);
    if (lane == 0) S[13] = 1.f/(sqrtf(sq)+1e-8f);
  }
  if (t == 128) {
    S[0] = softplusf_(ob[64]);
    S[1] = sigmoidf_(ob[65]);
    float m3 = fmaxf(ob[66], fmaxf(ob[67], ob[68]));
    float e0=expf(ob[66]-m3), e1=expf(ob[67]-m3), e2=expf(ob[68]-m3);
    float es = e0+e1+e2;
    S[2]=e0/es; S[3]=e1/es; S[4]=e2/es;
    S[5] = 1.f + softplusf_(ob[69]);
  }
  if (t == 129) {
    S[7] = softplusf_(ob[134]);
    S[8] = sigmoidf_(ob[135]);
    float m3 = fmaxf(ob[136], fmaxf(ob[137], ob[138]));
    float e0=expf(ob[136]-m3), e1=expf(ob[137]-m3), e2=expf(ob[138]-m3);
    float es = e0+e1+e2;
    S[9]=e0/es; S[10]=e1/es; S[11]=e2/es;
    S[12] = 1.f + softplusf_(ob[139]);
  }
}

// ---------------- Kernel 4: pass A over memory — beta*cosine-sim for both heads
__global__ __launch_bounds__(256) void k_sim(
    const float* __restrict__ mem, const float* __restrict__ params,
    float* __restrict__ a_r, float* __restrict__ a_w)
{
  int b = blockIdx.y;
  int n = blockIdx.x*16 + (threadIdx.x >> 4);
  int chunk = threadIdx.x & 15;
  float4 v = ((const float4*)mem)[(b*Nn + n)*16 + chunk];
  const float* P = params + b*PSTRIDE;
  float4 kr = ((const float4*)P)[chunk];
  float4 kw = ((const float4*)(P+64))[chunk];
  float ss = v.x*v.x + v.y*v.y + v.z*v.z + v.w*v.w;
  float pr = v.x*kr.x + v.y*kr.y + v.z*kr.z + v.w*kr.w;
  float pw = v.x*kw.x + v.y*kw.y + v.z*kw.z + v.w*kw.w;
  #pragma unroll
  for (int off=8; off; off>>=1) {
    ss += __shfl_xor(ss, off);
    pr += __shfl_xor(pr, off);
    pw += __shfl_xor(pw, off);
  }
  if (chunk == 0) {
    float inv_nm = 1.f/(sqrtf(ss)+1e-8f);
    const float* S = P + 256;
    a_r[b*Nn+n] = S[0] * pr * S[6]  * inv_nm;
    a_w[b*Nn+n] = S[7] * pw * S[13] * inv_nm;
  }
}

// ---------------- Kernel 5: softmax -> interpolate -> shift -> sharpen -> normalize
__device__ __forceinline__ float block_reduce512(float val, float* red, int t, bool ismax){
  #pragma unroll
  for (int off=32; off; off>>=1)
    val = ismax ? fmaxf(val, __shfl_xor(val,off)) : val + __shfl_xor(val,off);
  __syncthreads();
  if ((t&63)==0) red[t>>6] = val;
  __syncthreads();
  float r = red[0];
  if (ismax) { for (int i=1;i<8;++i) r = fmaxf(r, red[i]); }
  else       { for (int i=1;i<8;++i) r += red[i]; }
  return r;
}

__global__ __launch_bounds__(512) void k_weights(
    const float* __restrict__ a_r, const float* __restrict__ a_w,
    const float* __restrict__ read_w, const float* __restrict__ write_w,
    const float* __restrict__ params,
    float* __restrict__ w_read, float* __restrict__ w_write)
{
  __shared__ float wg[Nn];
  __shared__ float red[8];
  int b = blockIdx.x;
  int which = blockIdx.y;
  const float* a    = which ? a_w     : a_r;
  const float* prev = which ? write_w : read_w;
  float* outw       = which ? w_write : w_read;
  const float* S = params + b*PSTRIDE + 256 + (which ? 7 : 0);
  float g = S[1], s0 = S[2], s1 = S[3], s2 = S[4], gamma = S[5];
  int t = threadIdx.x;
  float v[4];
  #pragma unroll
  for (int i=0;i<4;++i) v[i] = a[b*Nn + t*4+i];
  float lmax = fmaxf(fmaxf(v[0],v[1]), fmaxf(v[2],v[3]));
  float mx = block_reduce512(lmax, red, t, true);
  float e[4]; float ps = 0.f;
  #pragma unroll
  for (int i=0;i<4;++i){ e[i] = expf(v[i]-mx); ps += e[i]; }
  float denom = block_reduce512(ps, red, t, false);
  float inv = 1.f/denom;
  #pragma unroll
  for (int i=0;i<4;++i){
    float wc = e[i]*inv;
    wg[t*4+i] = g*wc + (1.f-g)*prev[b*Nn + t*4+i];
  }
  __syncthreads();
  float wp[4]; float psum = 0.f;
  #pragma unroll
  for (int i=0;i<4;++i){
    int n = t*4+i;
    float wsv = s0*wg[(n+Nn-1)&(Nn-1)] + s1*wg[n] + s2*wg[(n+1)&(Nn-1)];
    wp[i] = powf(wsv, gamma);
    psum += wp[i];
  }
  float tot = block_reduce512(psum, red, t, false);
  float invt = 1.f/(tot + 1e-8f);
  #pragma unroll
  for (int i=0;i<4;++i) outw[b*Nn + t*4+i] = wp[i]*invt;
}

// ---------------- Kernel 6: pass B — memory_new + read_vec accumulation
__global__ __launch_bounds__(256) void k_memupd(
    const float* __restrict__ mem, const float* __restrict__ params,
    const float* __restrict__ w_read, const float* __restrict__ w_write,
    float* __restrict__ mem_new, float* __restrict__ read_vec)
{
  __shared__ __align__(16) float er[64];
  __shared__ __align__(16) float ad[64];
  __shared__ float4 part[64];
  int b = blockIdx.y;
  int n0 = blockIdx.x * 64;
  int t = threadIdx.x;
  const float* P = params + b*PSTRIDE;
  if (t < 64)       er[t]    = P[128+t];
  else if (t < 128) ad[t-64] = P[192+(t-64)];
  __syncthreads();
  int chunk = t & 15;
  int rr = t >> 4;
  float4 e4 = ((const float4*)er)[chunk];
  float4 a4 = ((const float4*)ad)[chunk];
  float4 acc = {0.f,0.f,0.f,0.f};
  #pragma unroll
  for (int p = 0; p < 4; ++p) {
    int n = n0 + p*16 + rr;
    float4 v = ((const float4*)mem)[(b*Nn+n)*16 + chunk];
    float ww = w_write[b*Nn+n];
    float wr = w_read[b*Nn+n];
    float4 o;
    o.x = v.x*(1.f-ww*e4.x) + ww*a4.x;
    o.y = v.y*(1.f-ww*e4.y) + ww*a4.y;
    o.z = v.z*(1.f-ww*e4.z) + ww*a4.z;
    o.w = v.w*(1.f-ww*e4.w) + ww*a4.w;
    ((float4*)mem_new)[(b*Nn+n)*16 + chunk] = o;
    acc.x += wr*v.x; acc.y += wr*v.y; acc.z += wr*v.z; acc.w += wr*v.w;
  }
  #pragma unroll
  for (int off = 16; off <= 32; off <<= 1) {
    acc.x += __shfl_xor(acc.x, off);
    acc.y += __shfl_xor(acc.y, off);
    acc.z += __shfl_xor(acc.z, off);
    acc.w += __shfl_xor(acc.w, off);
  }
  int wave = t >> 6;
  int lane = t & 63;
  if (lane < 16) part[wave*16 + chunk] = acc;
  __syncthreads();
  if (t < 16) {
    float4 s = part[t];
    for (int w=1; w<4; ++w){ float4 q = part[w*16+t]; s.x+=q.x; s.y+=q.y; s.z+=q.z; s.w+=q.w; }
    atomicAdd(&read_vec[b*64 + t*4+0], s.x);
    atomicAdd(&read_vec[b*64 + t*4+1], s.y);
    atomicAdd(&read_vec[b*64 + t*4+2], s.z);
    atomicAdd(&read_vec[b*64 + t*4+3], s.w);
  }
}

// ---------------- Kernel 7: out = [h_new, read_vec] @ W_o^T + b_o (coalesced)
__global__ __launch_bounds__(256) void k_out(
    const float* __restrict__ h_new, const float* __restrict__ read_vec,
    const float* __restrict__ W_o, const float* __restrict__ b_o,
    float* __restrict__ out)
{
  __shared__ float vbuf[576];
  int b = blockIdx.y, t = threadIdx.x;
  vbuf[t]     = h_new[b*CSd + t];
  vbuf[t+256] = h_new[b*CSd + t + 256];
  if (t < 64) vbuf[512+t] = read_vec[b*64 + t];
  __syncthreads();
  int wave = t >> 6, lane = t & 63;
  float vb[9];
  #pragma unroll
  for (int i = 0; i < 9; ++i) vb[i] = vbuf[i*64 + lane];
  int cbase = blockIdx.x*64 + wave*16;
  for (int jj = 0; jj < 16; ++jj) {
    int cc = cbase + jj;
    const float* w = W_o + cc*576;
    float s = 0.f;
    #pragma unroll
    for (int i = 0; i < 9; ++i) s += w[i*64 + lane] * vb[i];
    #pragma unroll
    for (int off = 32; off; off >>= 1) s += __shfl_xor(s, off);
    if (lane == 0) out[b*OUTd + cc] = s + b_o[cc];
  }
}

extern "C" void kernel_launch(void* const* d_in, const int* in_sizes, int n_in,
                              void* d_out, int out_size, void* d_ws, size_t ws_size,
                              hipStream_t stream)
{
  const float* x         = (const float*)d_in[0];
  const float* memory    = (const float*)d_in[1];
  const float* h         = (const float*)d_in[2];
  const float* c         = (const float*)d_in[3];
  const float* read_w    = (const float*)d_in[4];
  const float* write_w   = (const float*)d_in[5];
  const float* prev_read = (const float*)d_in[6];
  const float* W_ih      = (const float*)d_in[7];
  const float* W_hh      = (const float*)d_in[8];
  const float* b_ih      = (const float*)d_in[9];
  const float* b_hh      = (const float*)d_in[10];
  const float* W_r       = (const float*)d_in[11];
  const float* b_r       = (const float*)d_in[12];
  const float* W_w       = (const float*)d_in[13];
  const float* b_w       = (const float*)d_in[14];
  const float* W_o       = (const float*)d_in[15];
  const float* b_o       = (const float*)d_in[16];

  float* out      = (float*)d_out;
  float* mem_new  = out + 256*256;
  float* h_new    = mem_new + (size_t)256*2048*64;
  float* c_new    = h_new + 256*512;
  float* w_read   = c_new + 256*512;
  float* w_write  = w_read + 256*2048;
  float* read_vec = w_write + 256*2048;

  float* ws       = (float*)d_ws;
  float* params   = ws;                      // 256*PSTRIDE = 69632 floats
  float* partials = params + 256*PSTRIDE;    // 4 * 524288 floats (8 MB)
  // a_r/a_w alias partials: partials are dead after k_lstm, a_r/a_w born at k_sim
  float* a_r      = partials;                // 256*2048
  float* a_w      = partials + GSZ;          // 256*2048

  k_gates  <<<dim3(32,8,4), 256, 0, stream>>>(x, prev_read, h, W_ih, W_hh, partials);
  k_lstm   <<<512,          256, 0, stream>>>(partials, c, b_ih, b_hh, h_new, c_new);
  k_heads  <<<256,          512, 0, stream>>>(h_new, W_r, b_r, W_w, b_w, params);
  k_sim    <<<dim3(128,256),256, 0, stream>>>(memory, params, a_r, a_w);
  k_weights<<<dim3(256,2),  512, 0, stream>>>(a_r, a_w, read_w, write_w, params, w_read, w_write);
  hipMemsetAsync(read_vec, 0, 256*64*sizeof(float), stream);
  k_memupd <<<dim3(32,256), 256, 0, stream>>>(memory, params, w_read, w_write, mem_new, read_vec);
  k_out    <<<dim3(4,256),  256, 0, stream>>>(h_new, read_vec, W_o, b_o, out);
}

// Round 4
// 369.322 us; speedup vs baseline: 1.2602x; 1.0180x over previous
//
#include <hip/hip_runtime.h>
#include <math.h>

#define Bsz   256
#define Nn    2048
#define Md    64
#define CSd   512
#define INPd  256
#define OUTd  256
#define KTOT  832      // INP + M + CS
#define PSTRIDE 272    // per-batch param block (floats)
#define GSZ   524288   // 256*2048 gates elements (one split partial)
#define ZSPL  8        // K splits for gates GEMM
#define KZ    104      // K per split = 832/8 = 13*8

__device__ __forceinline__ float sigmoidf_(float x){ return 1.f/(1.f+expf(-x)); }
__device__ __forceinline__ float softplusf_(float x){ return fmaxf(x,0.f) + log1pf(expf(-fabsf(x))); }

__device__ __forceinline__ float4 loadA4(const float* __restrict__ x, const float* __restrict__ pr,
                                         const float* __restrict__ h, int row, int k){
  if (k < INPd)            return *(const float4*)&x[row*INPd + k];
  else if (k < INPd+Md)    return *(const float4*)&pr[row*Md + (k-INPd)];
  else                     return *(const float4*)&h[row*CSd + (k-INPd-Md)];
}
__device__ __forceinline__ float4 loadW4(const float* __restrict__ Wih, const float* __restrict__ Whh,
                                         int j, int k){
  if (k < INPd+Md)         return *(const float4*)&Wih[j*(INPd+Md) + k];
  else                     return *(const float4*)&Whh[j*CSd + (k-INPd-Md)];
}

// ---------------- Kernel 1: gates partials, split-K GEMM
// [256x832] @ [832x2048]^T, tile 64x64, BK=8, Z=8, 64 thr/blk, 8x8/thread
__global__ __launch_bounds__(64) void k_gates(
    const float* __restrict__ x, const float* __restrict__ prev_read, const float* __restrict__ h,
    const float* __restrict__ W_ih, const float* __restrict__ W_hh,
    float* __restrict__ partials)
{
  __shared__ __align__(16) float As[8][68];   // [k][row], stride 272B
  __shared__ __align__(16) float Bs[8][68];   // [k][col]
  const int t = threadIdx.x;             // 0..63
  const int col0 = blockIdx.x * 64;
  const int row0 = blockIdx.y * 64;
  const int z    = blockIdx.z;
  const int tr = t >> 3, tc = t & 7;     // 8x8 thread grid
  const int row = row0 + t;              // A-stage row
  const int j   = col0 + t;              // B-stage col

  float acc[8][8] = {};
  float4 a0, a1, b0, b1;
  int kb = z * KZ;
  a0 = loadA4(x, prev_read, h, row, kb);   a1 = loadA4(x, prev_read, h, row, kb+4);
  b0 = loadW4(W_ih, W_hh, j, kb);          b1 = loadW4(W_ih, W_hh, j, kb+4);

  for (int kc = 0; kc < 13; ++kc) {
    // commit staged regs to LDS (transposed)
    As[0][t]=a0.x; As[1][t]=a0.y; As[2][t]=a0.z; As[3][t]=a0.w;
    As[4][t]=a1.x; As[5][t]=a1.y; As[6][t]=a1.z; As[7][t]=a1.w;
    Bs[0][t]=b0.x; Bs[1][t]=b0.y; Bs[2][t]=b0.z; Bs[3][t]=b0.w;
    Bs[4][t]=b1.x; Bs[5][t]=b1.y; Bs[6][t]=b1.z; Bs[7][t]=b1.w;
    __syncthreads();
    // prefetch next slab while computing
    if (kc < 12) {
      int kn = kb + (kc+1)*8;
      a0 = loadA4(x, prev_read, h, row, kn);   a1 = loadA4(x, prev_read, h, row, kn+4);
      b0 = loadW4(W_ih, W_hh, j, kn);          b1 = loadW4(W_ih, W_hh, j, kn+4);
    }
    #pragma unroll
    for (int kk = 0; kk < 8; ++kk) {
      float av[8], bv[8];
      *(float4*)&av[0] = *(const float4*)&As[kk][tr*8];
      *(float4*)&av[4] = *(const float4*)&As[kk][tr*8+4];
      *(float4*)&bv[0] = *(const float4*)&Bs[kk][tc*8];
      *(float4*)&bv[4] = *(const float4*)&Bs[kk][tc*8+4];
      #pragma unroll
      for (int i=0;i<8;++i)
        #pragma unroll
        for (int q=0;q<8;++q)
          acc[i][q] += av[i]*bv[q];
    }
    __syncthreads();
  }
  float* part = partials + (size_t)z * GSZ;
  #pragma unroll
  for (int i=0;i<8;++i) {
    int r = row0 + tr*8 + i;
    float4 v0 = {acc[i][0],acc[i][1],acc[i][2],acc[i][3]};
    float4 v1 = {acc[i][4],acc[i][5],acc[i][6],acc[i][7]};
    *(float4*)&part[r*2048 + col0 + tc*8]     = v0;
    *(float4*)&part[r*2048 + col0 + tc*8 + 4] = v1;
  }
}

// ---------------- Kernel 2: fused LSTM elementwise + head projections + params
__global__ __launch_bounds__(512) void k_lstm_heads(
    const float* __restrict__ partials, const float* __restrict__ c,
    const float* __restrict__ b_ih, const float* __restrict__ b_hh,
    const float* __restrict__ W_r, const float* __restrict__ b_r,
    const float* __restrict__ W_w, const float* __restrict__ b_w,
    float* __restrict__ h_new, float* __restrict__ c_new, float* __restrict__ params)
{
  __shared__ float hs[CSd];
  __shared__ float ob[268];
  int b = blockIdx.x, t = threadIdx.x;
  // --- LSTM: thread t owns element (b, t)
  float g[4];
  #pragma unroll
  for (int q = 0; q < 4; ++q) {
    int col = q*512 + t;
    float s = b_ih[col] + b_hh[col];
    #pragma unroll
    for (int sp = 0; sp < ZSPL; ++sp) s += partials[(size_t)sp*GSZ + b*2048 + col];
    g[q] = s;
  }
  float ig = sigmoidf_(g[0]);
  float fg = sigmoidf_(g[1]);
  float gg = tanhf(g[2]);
  float og = sigmoidf_(g[3]);
  float cn = fg * c[b*CSd + t] + ig * gg;
  float hn = og * tanhf(cn);
  c_new[b*CSd + t] = cn;
  h_new[b*CSd + t] = hn;
  hs[t] = hn;
  __syncthreads();
  // --- heads: wave-per-row coalesced GEMV
  int wave = t >> 6, lane = t & 63;
  for (int r = wave; r < 268; r += 8) {
    const float* wrow; float bias;
    if (r < 70) { wrow = W_r + r*CSd;      bias = b_r[r]; }
    else        { wrow = W_w + (r-70)*CSd; bias = b_w[r-70]; }
    float s = 0.f;
    #pragma unroll
    for (int i = 0; i < 8; ++i) s += wrow[i*64 + lane] * hs[i*64 + lane];
    #pragma unroll
    for (int off = 32; off; off >>= 1) s += __shfl_xor(s, off);
    if (lane == 0) ob[r] = s + bias;
  }
  __syncthreads();
  float* P = params + b*PSTRIDE;
  if (t < 256) {
    if (t < 64)       P[t] = ob[t];                           // k_r
    else if (t < 128) P[t] = ob[70 + (t-64)];                 // k_w
    else if (t < 192) P[t] = sigmoidf_(ob[140 + (t-128)]);    // erase
    else              P[t] = ob[204 + (t-192)];               // add
  }
  float* S = P + 256;
  if (wave == 0) {
    float v = ob[lane]; float sq = v*v;
    #pragma unroll
    for (int off = 32; off; off >>= 1) sq += __shfl_xor(sq, off);
    if (lane == 0) S[6] = 1.f/(sqrtf(sq)+1e-8f);
  } else if (wave == 1) {
    float v = ob[70 + lane]; float sq = v*v;
    #pragma unroll
    for (int off = 32; off; off >>= 1) sq += __shfl_xor(sq, off);
    if (lane == 0) S[13] = 1.f/(sqrtf(sq)+1e-8f);
  }
  if (t == 128) {
    S[0] = softplusf_(ob[64]);
    S[1] = sigmoidf_(ob[65]);
    float m3 = fmaxf(ob[66], fmaxf(ob[67], ob[68]));
    float e0=expf(ob[66]-m3), e1=expf(ob[67]-m3), e2=expf(ob[68]-m3);
    float es = e0+e1+e2;
    S[2]=e0/es; S[3]=e1/es; S[4]=e2/es;
    S[5] = 1.f + softplusf_(ob[69]);
  }
  if (t == 129) {
    S[7] = softplusf_(ob[134]);
    S[8] = sigmoidf_(ob[135]);
    float m3 = fmaxf(ob[136], fmaxf(ob[137], ob[138]));
    float e0=expf(ob[136]-m3), e1=expf(ob[137]-m3), e2=expf(ob[138]-m3);
    float es = e0+e1+e2;
    S[9]=e0/es; S[10]=e1/es; S[11]=e2/es;
    S[12] = 1.f + softplusf_(ob[139]);
  }
}

// ---------------- Kernel 3: pass A over memory — beta*cosine-sim for both heads
__global__ __launch_bounds__(256) void k_sim(
    const float* __restrict__ mem, const float* __restrict__ params,
    float* __restrict__ a_r, float* __restrict__ a_w)
{
  int b = blockIdx.y;
  int n = blockIdx.x*16 + (threadIdx.x >> 4);
  int chunk = threadIdx.x & 15;
  float4 v = ((const float4*)mem)[(b*Nn + n)*16 + chunk];
  const float* P = params + b*PSTRIDE;
  float4 kr = ((const float4*)P)[chunk];
  float4 kw = ((const float4*)(P+64))[chunk];
  float ss = v.x*v.x + v.y*v.y + v.z*v.z + v.w*v.w;
  float pr = v.x*kr.x + v.y*kr.y + v.z*kr.z + v.w*kr.w;
  float pw = v.x*kw.x + v.y*kw.y + v.z*kw.z + v.w*kw.w;
  #pragma unroll
  for (int off=8; off; off>>=1) {
    ss += __shfl_xor(ss, off);
    pr += __shfl_xor(pr, off);
    pw += __shfl_xor(pw, off);
  }
  if (chunk == 0) {
    float inv_nm = 1.f/(sqrtf(ss)+1e-8f);
    const float* S = P + 256;
    a_r[b*Nn+n] = S[0] * pr * S[6]  * inv_nm;
    a_w[b*Nn+n] = S[7] * pw * S[13] * inv_nm;
  }
}

// ---------------- Kernel 4: softmax -> interpolate -> shift -> sharpen -> normalize
__device__ __forceinline__ float block_reduce512(float val, float* red, int t, bool ismax){
  #pragma unroll
  for (int off=32; off; off>>=1)
    val = ismax ? fmaxf(val, __shfl_xor(val,off)) : val + __shfl_xor(val,off);
  __syncthreads();
  if ((t&63)==0) red[t>>6] = val;
  __syncthreads();
  float r = red[0];
  if (ismax) { for (int i=1;i<8;++i) r = fmaxf(r, red[i]); }
  else       { for (int i=1;i<8;++i) r += red[i]; }
  return r;
}

__global__ __launch_bounds__(512) void k_weights(
    const float* __restrict__ a_r, const float* __restrict__ a_w,
    const float* __restrict__ read_w, const float* __restrict__ write_w,
    const float* __restrict__ params,
    float* __restrict__ w_read, float* __restrict__ w_write)
{
  __shared__ float wg[Nn];
  __shared__ float red[8];
  int b = blockIdx.x;
  int which = blockIdx.y;
  const float* a    = which ? a_w     : a_r;
  const float* prev = which ? write_w : read_w;
  float* outw       = which ? w_write : w_read;
  const float* S = params + b*PSTRIDE + 256 + (which ? 7 : 0);
  float g = S[1], s0 = S[2], s1 = S[3], s2 = S[4], gamma = S[5];
  int t = threadIdx.x;
  float v[4];
  #pragma unroll
  for (int i=0;i<4;++i) v[i] = a[b*Nn + t*4+i];
  float lmax = fmaxf(fmaxf(v[0],v[1]), fmaxf(v[2],v[3]));
  float mx = block_reduce512(lmax, red, t, true);
  float e[4]; float ps = 0.f;
  #pragma unroll
  for (int i=0;i<4;++i){ e[i] = expf(v[i]-mx); ps += e[i]; }
  float denom = block_reduce512(ps, red, t, false);
  float inv = 1.f/denom;
  #pragma unroll
  for (int i=0;i<4;++i){
    float wc = e[i]*inv;
    wg[t*4+i] = g*wc + (1.f-g)*prev[b*Nn + t*4+i];
  }
  __syncthreads();
  float wp[4]; float psum = 0.f;
  #pragma unroll
  for (int i=0;i<4;++i){
    int n = t*4+i;
    float wsv = s0*wg[(n+Nn-1)&(Nn-1)] + s1*wg[n] + s2*wg[(n+1)&(Nn-1)];
    wp[i] = powf(wsv, gamma);
    psum += wp[i];
  }
  float tot = block_reduce512(psum, red, t, false);
  float invt = 1.f/(tot + 1e-8f);
  #pragma unroll
  for (int i=0;i<4;++i) outw[b*Nn + t*4+i] = wp[i]*invt;
}

// ---------------- Kernel 5: pass B — memory_new + read_vec block partials
__global__ __launch_bounds__(256) void k_memupd(
    const float* __restrict__ mem, const float* __restrict__ params,
    const float* __restrict__ w_read, const float* __restrict__ w_write,
    float* __restrict__ mem_new, float* __restrict__ prv)
{
  __shared__ __align__(16) float er[64];
  __shared__ __align__(16) float ad[64];
  __shared__ float4 part[64];
  int b = blockIdx.y;
  int n0 = blockIdx.x * 64;
  int t = threadIdx.x;
  const float* P = params + b*PSTRIDE;
  if (t < 64)       er[t]    = P[128+t];
  else if (t < 128) ad[t-64] = P[192+(t-64)];
  __syncthreads();
  int chunk = t & 15;
  int rr = t >> 4;
  float4 e4 = ((const float4*)er)[chunk];
  float4 a4 = ((const float4*)ad)[chunk];
  float4 acc = {0.f,0.f,0.f,0.f};
  #pragma unroll
  for (int p = 0; p < 4; ++p) {
    int n = n0 + p*16 + rr;
    float4 v = ((const float4*)mem)[(b*Nn+n)*16 + chunk];
    float ww = w_write[b*Nn+n];
    float wr = w_read[b*Nn+n];
    float4 o;
    o.x = v.x*(1.f-ww*e4.x) + ww*a4.x;
    o.y = v.y*(1.f-ww*e4.y) + ww*a4.y;
    o.z = v.z*(1.f-ww*e4.z) + ww*a4.z;
    o.w = v.w*(1.f-ww*e4.w) + ww*a4.w;
    ((float4*)mem_new)[(b*Nn+n)*16 + chunk] = o;
    acc.x += wr*v.x; acc.y += wr*v.y; acc.z += wr*v.z; acc.w += wr*v.w;
  }
  #pragma unroll
  for (int off = 16; off <= 32; off <<= 1) {
    acc.x += __shfl_xor(acc.x, off);
    acc.y += __shfl_xor(acc.y, off);
    acc.z += __shfl_xor(acc.z, off);
    acc.w += __shfl_xor(acc.w, off);
  }
  int wave = t >> 6;
  if ((t & 63) < 16) part[wave*16 + chunk] = acc;
  __syncthreads();
  if (t < 16) {
    float4 s = part[t];
    for (int w=1; w<4; ++w){ float4 q = part[w*16+t]; s.x+=q.x; s.y+=q.y; s.z+=q.z; s.w+=q.w; }
    *(float4*)&prv[(b*32 + blockIdx.x)*64 + t*4] = s;
  }
}

// ---------------- Kernel 6: reduce read_vec + out GEMV
__global__ __launch_bounds__(256) void k_out(
    const float* __restrict__ h_new, const float* __restrict__ prv,
    const float* __restrict__ W_o, const float* __restrict__ b_o,
    float* __restrict__ out, float* __restrict__ read_vec)
{
  __shared__ float vbuf[576];
  int b = blockIdx.y, t = threadIdx.x;
  vbuf[t]     = h_new[b*CSd + t];
  vbuf[t+256] = h_new[b*CSd + t + 256];
  if (t < 64) {
    float s = 0.f;
    #pragma unroll 8
    for (int i = 0; i < 32; ++i) s += prv[(b*32 + i)*64 + t];
    vbuf[512+t] = s;
    if (blockIdx.x == 0) read_vec[b*64 + t] = s;
  }
  __syncthreads();
  int wave = t >> 6, lane = t & 63;
  float vb[9];
  #pragma unroll
  for (int i = 0; i < 9; ++i) vb[i] = vbuf[i*64 + lane];
  int cbase = blockIdx.x*64 + wave*16;
  for (int jj = 0; jj < 16; ++jj) {
    int cc = cbase + jj;
    const float* w = W_o + cc*576;
    float s = 0.f;
    #pragma unroll
    for (int i = 0; i < 9; ++i) s += w[i*64 + lane] * vb[i];
    #pragma unroll
    for (int off = 32; off; off >>= 1) s += __shfl_xor(s, off);
    if (lane == 0) out[b*OUTd + cc] = s + b_o[cc];
  }
}

extern "C" void kernel_launch(void* const* d_in, const int* in_sizes, int n_in,
                              void* d_out, int out_size, void* d_ws, size_t ws_size,
                              hipStream_t stream)
{
  const float* x         = (const float*)d_in[0];
  const float* memory    = (const float*)d_in[1];
  const float* h         = (const float*)d_in[2];
  const float* c         = (const float*)d_in[3];
  const float* read_w    = (const float*)d_in[4];
  const float* write_w   = (const float*)d_in[5];
  const float* prev_read = (const float*)d_in[6];
  const float* W_ih      = (const float*)d_in[7];
  const float* W_hh      = (const float*)d_in[8];
  const float* b_ih      = (const float*)d_in[9];
  const float* b_hh      = (const float*)d_in[10];
  const float* W_r       = (const float*)d_in[11];
  const float* b_r       = (const float*)d_in[12];
  const float* W_w       = (const float*)d_in[13];
  const float* b_w       = (const float*)d_in[14];
  const float* W_o       = (const float*)d_in[15];
  const float* b_o       = (const float*)d_in[16];

  float* out      = (float*)d_out;
  float* mem_new  = out + 256*256;
  float* h_new    = mem_new + (size_t)256*2048*64;
  float* c_new    = h_new + 256*512;
  float* w_read   = c_new + 256*512;
  float* w_write  = w_read + 256*2048;
  float* read_vec = w_write + 256*2048;

  float* ws       = (float*)d_ws;
  float* params   = ws;                      // 256*PSTRIDE floats
  float* partials = params + 256*PSTRIDE;    // 8 * GSZ floats (16 MB)
  // aliases into dead partials space (sequential stream ordering makes this safe):
  float* a_r      = partials;                // live k_sim -> k_weights
  float* a_w      = partials + GSZ;
  float* prv      = partials + 2*GSZ;        // live k_memupd -> k_out (256*32*64)

  k_gates     <<<dim3(32,4,ZSPL), 64, 0, stream>>>(x, prev_read, h, W_ih, W_hh, partials);
  k_lstm_heads<<<256,            512, 0, stream>>>(partials, c, b_ih, b_hh, W_r, b_r, W_w, b_w,
                                                   h_new, c_new, params);
  k_sim       <<<dim3(128,256),  256, 0, stream>>>(memory, params, a_r, a_w);
  k_weights   <<<dim3(256,2),    512, 0, stream>>>(a_r, a_w, read_w, write_w, params, w_read, w_write);
  k_memupd    <<<dim3(32,256),   256, 0, stream>>>(memory, params, w_read, w_write, mem_new, prv);
  k_out       <<<dim3(4,256),    256, 0, stream>>>(h_new, prv, W_o, b_o, out, read_vec);
}